// Round 1
// 113.110 us; speedup vs baseline: 1.0023x; 1.0023x over previous
//
#include <hip/hip_runtime.h>

#define NT 32768
#define DI 36
#define HH 64
#define LH 20
#define TPB 32            // timesteps per block (2 MFMA column cohorts)
#define NROW 51           // staged emb rows = TPB + LH - 1
#define SGS 196           // Sg row stride (floats), 16B-aligned, odd granule
#define EMBS 40           // Emb row stride (ushorts): 80B = 5 granules (odd) -> conflict-free

#define NLOG2E -1.4426950408889634f   // r/z pre-scale: sigmoid(x)=rcp(1+exp2(-x*log2e))
#define TLOG2E 2.8853900817779268f    // n pre-scale: tanh(x)=1-2*rcp(1+exp2(2x*log2e))

// shared memory map (bytes):
//   [0, 39984)        Sg: float[51][196] gi slices (fp32), wave-private cols;
//                     reused as Hid[32][68] f32 for the MLP epilogue
//   [39984, 49200)    UNION (disjoint lifetimes):
//                       phase 0/1: EmbH[51][40] + EmbL[51][40] ushort (8160B)
//                       phase 2:   Hb[2][32*72] ushort h exchange (9216B)
//                       phase 3:   HfH[32*72] + HfL[32*72] ushort (9216B)
//   [49200, 49328)    sfirst[32]
#define UNION_OFF  39984
#define SFIRST_OFF 49200
#define SMEM_BYTES 49328   // x3 = 147984 <= 160KB -> 3 blocks/CU

typedef __attribute__((ext_vector_type(8))) short bf16x8;
typedef __attribute__((ext_vector_type(4))) float f32x4;
typedef __attribute__((ext_vector_type(4))) int int4v;
union frag_cast { int4v i4; bf16x8 h8; };

__device__ __forceinline__ unsigned f2u(float f) { union { float f; unsigned u; } x; x.f = f; return x.u; }
__device__ __forceinline__ float u2f(unsigned u) { union { float f; unsigned u; } x; x.u = u; return x.f; }
__device__ __forceinline__ unsigned short f2bf_rne(float f) {
    union { float f; unsigned u; } x; x.f = f;
    unsigned r = x.u + 0x7FFFu + ((x.u >> 16) & 1u);
    return (unsigned short)(r >> 16);
}

// Prep: pre-packed A-fragments, coalesced-consumable by gru.
// frags 0..23: W_ih hi (trunc, scaled) | 24..47: W_ih lo | 48..71: W_hh hi (RNE, scaled)
// frags 72..79: W1 hi (trunc) | 80..87: W1 lo
// A-frag convention: lane l holds A[m=16mt+(l&15)][k=32kt+8(l>>4)+jj].
__global__ __launch_bounds__(64) void prep_kernel(
    const float* __restrict__ W_ih, const float* __restrict__ W_hh,
    const float* __restrict__ W1, int4v* __restrict__ wfrag)
{
    const int b = (int)blockIdx.x;         // 0..87
    const int l = (int)threadIdx.x;
    unsigned short e[8];
    if (b < 72) {
        const int set = b / 24, fb = b % 24;
        const int mt = fb >> 1, kt = fb & 1;
        const int m = mt * 16 + (l & 15);  // j row 0..191
        const float sc = ((mt >> 2) < 2) ? NLOG2E : TLOG2E;
        const int k0 = kt * 32 + (l >> 4) * 8;
#pragma unroll
        for (int jj = 0; jj < 8; ++jj) {
            const int k = k0 + jj;
            if (set == 2) {
                e[jj] = f2bf_rne(W_hh[(size_t)m * HH + k] * sc);
            } else {
                const float v = (k < DI) ? W_ih[(size_t)m * DI + k] * sc : 0.f;
                const unsigned u = f2u(v);
                if (set == 0) e[jj] = (unsigned short)(u >> 16);   // trunc hi
                else          e[jj] = (unsigned short)(f2u(v - u2f(u & 0xFFFF0000u)) >> 16);
            }
        }
    } else {
        const int bb = b - 72;             // 0..15
        const bool is_lo = bb >= 8;
        const int f = bb & 7;
        const int mt = f >> 1, kt = f & 1;
        const int m = mt * 16 + (l & 15);  // 0..63
        const int k0 = kt * 32 + (l >> 4) * 8;
#pragma unroll
        for (int jj = 0; jj < 8; ++jj) {
            const float v = W1[(size_t)m * HH + k0 + jj];
            const unsigned u = f2u(v);
            if (!is_lo) e[jj] = (unsigned short)(u >> 16);         // trunc hi
            else        e[jj] = (unsigned short)(f2u(v - u2f(u & 0xFFFF0000u)) >> 16);
        }
    }
    int4v p;
    p.x = e[0] | ((unsigned)e[1] << 16); p.y = e[2] | ((unsigned)e[3] << 16);
    p.z = e[4] | ((unsigned)e[5] << 16); p.w = e[6] | ((unsigned)e[7] << 16);
    wfrag[b * 64 + l] = p;
}

// Fused kernel: 1024 blocks x 256 thr (4 waves), 32 timesteps/block.
// Phase 1: in-block gi-GEMM (W_ih hi/lo x emb hi/lo) -> Sg LDS, 4 row-tiles.
// Phase 2: recurrence, 4-way j-split x 2 t-cohorts; h carried bf16-HI-only into
//          MFMA (fp32 h in regs): 12 MFMA + 4 b128 + 2 b64-write per wave-step,
//          one barrier per step (2x work per barrier vs 16t version).
// Phase 3: MLP1 via MFMA (h hi/lo exact), MLP2 scalar.
__global__ __launch_bounds__(256, 3) void gru_kernel(
    const float* __restrict__ emb, const int4v* __restrict__ wfrag,
    const float* __restrict__ b_ih, const float* __restrict__ b_hh,
    const float* __restrict__ b1, const float* __restrict__ W2,
    const float* __restrict__ b2, const int* __restrict__ dones,
    float* __restrict__ out)
{
    __shared__ __align__(16) char SMEM[SMEM_BYTES];
    float* const Sg = (float*)SMEM;
    unsigned short* const EmbH = (unsigned short*)(SMEM + UNION_OFF);  // [51][40]
    unsigned short* const EmbL = EmbH + NROW * EMBS;
    unsigned short* const HbB  = (unsigned short*)(SMEM + UNION_OFF);  // [2][32*72]
    unsigned short* const HfH  = (unsigned short*)(SMEM + UNION_OFF);  // [32*72]
    unsigned short* const HfL  = HfH + 2304;
    int* const sfirst = (int*)(SMEM + SFIRST_OFF);

    const int tid = threadIdx.x;
    const int lane = tid & 63;
    const int W = tid >> 6;          // wave id = j-quarter owner
    const int li = lane & 15;        // t within cohort (MFMA col)
    const int q = lane >> 4;         // quad
    const int blk = ((int)blockIdx.x & 7) * 128 + ((int)blockIdx.x >> 3);
    const int T0 = blk * TPB;

    // ---- Phase 0: zero Emb staging (pad cols 36..39 must be 0), window starts ----
    {
        int4v* z = (int4v*)EmbH;
        for (int i = tid; i < 510; i += 256) z[i] = int4v{0, 0, 0, 0};
    }
    if (tid < TPB) {                 // window start: dones[t-19..t-1] only
        const int tt = T0 + tid;
        int lo = tt - (LH - 1); if (lo < 0) lo = 0;
        int ws = lo;
        for (int j = lo; j < tt; ++j)
            ws = (dones[j] != 0) ? (j + 1) : ws;
        sfirst[tid] = ws - (tt - (LH - 1));
    }
    __syncthreads();
    for (int i = tid; i < NROW * DI; i += 256) {   // fill rows 0..50
        const int r = i / DI, c = i % DI;
        int tt = T0 - (LH - 1) + r; tt = tt < 0 ? 0 : tt;
        const float v = emb[(size_t)tt * DI + c];
        const unsigned u = f2u(v);
        EmbH[r * EMBS + c] = (unsigned short)(u >> 16);
        EmbL[r * EMBS + c] = (unsigned short)(f2u(v - u2f(u & 0xFFFF0000u)) >> 16);
    }

    // ---- W fragments: 18 coalesced b128 loads (wave W -> tiles mt=4g+W) ----
    bf16x8 aih[3][2], ail[3][2], whh[3][2];
#pragma unroll
    for (int g = 0; g < 3; ++g)
#pragma unroll
        for (int kt = 0; kt < 2; ++kt) {
            const int fb = (4 * g + W) * 2 + kt;
            frag_cast a, b, c;
            a.i4 = wfrag[(0 * 24 + fb) * 64 + lane];
            b.i4 = wfrag[(1 * 24 + fb) * 64 + lane];
            c.i4 = wfrag[(2 * 24 + fb) * 64 + lane];
            aih[g][kt] = a.h8; ail[g][kt] = b.h8; whh[g][kt] = c.h8;
        }

    const int joff = 16 * W + 4 * q; // this thread's j' base within each gate
    f32x4 biasI[3];                  // gi-GEMM acc init = (b_ih + b_hh_rz) * sc
#pragma unroll
    for (int g = 0; g < 3; ++g) {
        const float sc = (g < 2) ? NLOG2E : TLOG2E;
        const f32x4 bi = *(const f32x4*)&b_ih[64 * g + joff];
        if (g < 2) {
            const f32x4 bh = *(const f32x4*)&b_hh[64 * g + joff];
#pragma unroll
            for (int rr = 0; rr < 4; ++rr) biasI[g][rr] = (bi[rr] + bh[rr]) * sc;
        } else {
#pragma unroll
            for (int rr = 0; rr < 4; ++rr) biasI[g][rr] = bi[rr] * sc;
        }
    }
    f32x4 bnv;                       // n-gate step init = 2*log2e * b_hh_n
    {
        const f32x4 b = *(const f32x4*)&b_hh[128 + joff];
#pragma unroll
        for (int rr = 0; rr < 4; ++rr) bnv[rr] = b[rr] * TLOG2E;
    }
    __syncthreads();                 // Emb staged

    // ---- Phase 1: gi-GEMM -> Sg. Row-tiles {0,16,32,35}: rows 35..47 are
    //      recomputed bit-identically by tile 3 (benign same-wave rewrite),
    //      so no Emb/Sg row >= 51 is ever touched. kt=1 B-frag: only q==0
    //      lanes carry real data (k=32..39); q>0 lanes are register zeros. ----
#pragma unroll
    for (int nt = 0; nt < 4; ++nt) {
        const int row = ((nt == 3) ? 35 : 16 * nt) + li;
        bf16x8 ebh0 = *(const bf16x8*)&EmbH[row * EMBS + 8 * q];
        bf16x8 ebl0 = *(const bf16x8*)&EmbL[row * EMBS + 8 * q];
        bf16x8 ebh1 = bf16x8{0, 0, 0, 0, 0, 0, 0, 0};
        bf16x8 ebl1 = bf16x8{0, 0, 0, 0, 0, 0, 0, 0};
        if (q == 0) {
            ebh1 = *(const bf16x8*)&EmbH[row * EMBS + 32];
            ebl1 = *(const bf16x8*)&EmbL[row * EMBS + 32];
        }
#pragma unroll
        for (int g = 0; g < 3; ++g) {
            f32x4 a = biasI[g];
            a = __builtin_amdgcn_mfma_f32_16x16x32_bf16(aih[g][0], ebh0, a, 0, 0, 0);
            a = __builtin_amdgcn_mfma_f32_16x16x32_bf16(aih[g][1], ebh1, a, 0, 0, 0);
            a = __builtin_amdgcn_mfma_f32_16x16x32_bf16(ail[g][0], ebh0, a, 0, 0, 0);
            a = __builtin_amdgcn_mfma_f32_16x16x32_bf16(ail[g][1], ebh1, a, 0, 0, 0);
            a = __builtin_amdgcn_mfma_f32_16x16x32_bf16(aih[g][0], ebl0, a, 0, 0, 0);
            a = __builtin_amdgcn_mfma_f32_16x16x32_bf16(aih[g][1], ebl1, a, 0, 0, 0);
            *(f32x4*)&Sg[row * SGS + 64 * g + joff] = a;
        }
    }
    __syncthreads();                 // all waves past Emb reads (Hb aliases Emb)
    const int sfr[2] = { sfirst[li], sfirst[16 + li] };

    // ---- Phase 2: recurrence (h-hi only through MFMA), 2 t-cohorts/step ----
    float h[2][4];
    f32x4 gv0[2], gv1[2], gv2[2];    // LDS->reg gi prefetch for step s+1

    {   // s = 0 (h=0: no MFMA), writes buf1 for s=1
#pragma unroll
        for (int nt = 0; nt < 2; ++nt) {
            const float* gp = Sg + (16 * nt + li) * SGS;
            const f32x4 aR = *(const f32x4*)(gp + joff);
            const f32x4 aZ = *(const f32x4*)(gp + 64 + joff);
            const f32x4 gI = *(const f32x4*)(gp + 128 + joff);
            const bool valid = (0 >= sfr[nt]);
#pragma unroll
            for (int rr = 0; rr < 4; ++rr) {
                const float r  = __builtin_amdgcn_rcpf(1.f + __builtin_amdgcn_exp2f(aR[rr]));
                const float z  = __builtin_amdgcn_rcpf(1.f + __builtin_amdgcn_exp2f(aZ[rr]));
                const float nc = 1.f - 2.f * __builtin_amdgcn_rcpf(1.f + __builtin_amdgcn_exp2f(gI[rr] + r * bnv[rr]));
                h[nt][rr] = valid ? fmaf(z, 0.f - nc, nc) : 0.f;
            }
            uint2 ph;
            ph.x = __builtin_amdgcn_perm(f2u(h[nt][1]), f2u(h[nt][0]), 0x07060302u);
            ph.y = __builtin_amdgcn_perm(f2u(h[nt][3]), f2u(h[nt][2]), 0x07060302u);
            *(uint2*)&HbB[2304 + (16 * nt + li) * 72 + joff] = ph;
            // prefetch gi for s=1
            const float* gq = Sg + (16 * nt + li + 1) * SGS;
            gv0[nt] = *(const f32x4*)(gq + joff);
            gv1[nt] = *(const f32x4*)(gq + 64 + joff);
            gv2[nt] = *(const f32x4*)(gq + 128 + joff);
        }
    }
    __syncthreads();

#pragma unroll 2
    for (int s = 1; s < LH; ++s) {
        const int rb = s & 1;        // read buffer; write buffer = 1-rb
        bf16x8 bh0[2], bh1[2];
#pragma unroll
        for (int nt = 0; nt < 2; ++nt) {
            bh0[nt] = *(const bf16x8*)&HbB[rb * 2304 + (16 * nt + li) * 72 + 8 * q];
            bh1[nt] = *(const bf16x8*)&HbB[rb * 2304 + (16 * nt + li) * 72 + 32 + 8 * q];
        }
        f32x4 aR[2], aZ[2], aN[2], gI[2];
#pragma unroll
        for (int nt = 0; nt < 2; ++nt) {
            aR[nt] = gv0[nt]; aZ[nt] = gv1[nt]; gI[nt] = gv2[nt]; aN[nt] = bnv;
        }
#pragma unroll
        for (int nt = 0; nt < 2; ++nt) {   // prefetch s+1's gi (row clamped)
            int r = 16 * nt + li + s + 1; r = r > NROW - 1 ? NROW - 1 : r;
            const float* gq = Sg + r * SGS;
            gv0[nt] = *(const f32x4*)(gq + joff);
            gv1[nt] = *(const f32x4*)(gq + 64 + joff);
            gv2[nt] = *(const f32x4*)(gq + 128 + joff);
        }
#pragma unroll
        for (int nt = 0; nt < 2; ++nt) {
            aR[nt] = __builtin_amdgcn_mfma_f32_16x16x32_bf16(whh[0][0], bh0[nt], aR[nt], 0, 0, 0);
            aR[nt] = __builtin_amdgcn_mfma_f32_16x16x32_bf16(whh[0][1], bh1[nt], aR[nt], 0, 0, 0);
            aZ[nt] = __builtin_amdgcn_mfma_f32_16x16x32_bf16(whh[1][0], bh0[nt], aZ[nt], 0, 0, 0);
            aZ[nt] = __builtin_amdgcn_mfma_f32_16x16x32_bf16(whh[1][1], bh1[nt], aZ[nt], 0, 0, 0);
            aN[nt] = __builtin_amdgcn_mfma_f32_16x16x32_bf16(whh[2][0], bh0[nt], aN[nt], 0, 0, 0);
            aN[nt] = __builtin_amdgcn_mfma_f32_16x16x32_bf16(whh[2][1], bh1[nt], aN[nt], 0, 0, 0);
        }
#pragma unroll
        for (int nt = 0; nt < 2; ++nt) {
            const bool valid = (s >= sfr[nt]);
#pragma unroll
            for (int rr = 0; rr < 4; ++rr) {
                const float r  = __builtin_amdgcn_rcpf(1.f + __builtin_amdgcn_exp2f(aR[nt][rr]));
                const float z  = __builtin_amdgcn_rcpf(1.f + __builtin_amdgcn_exp2f(aZ[nt][rr]));
                const float nc = 1.f - 2.f * __builtin_amdgcn_rcpf(1.f + __builtin_amdgcn_exp2f(gI[nt][rr] + r * aN[nt][rr]));
                const float hn = fmaf(z, h[nt][rr] - nc, nc);
                h[nt][rr] = valid ? hn : h[nt][rr];
            }
            if (s != LH - 1) {
                uint2 ph;
                ph.x = __builtin_amdgcn_perm(f2u(h[nt][1]), f2u(h[nt][0]), 0x07060302u);
                ph.y = __builtin_amdgcn_perm(f2u(h[nt][3]), f2u(h[nt][2]), 0x07060302u);
                *(uint2*)&HbB[(1 - rb) * 2304 + (16 * nt + li) * 72 + joff] = ph;
            }
        }
        __syncthreads();             // LDS-only drain (cheap)
    }

    // ---- Phase 3: MLP. Final h -> hi/lo planes (exact), MLP1 via MFMA ----
#pragma unroll
    for (int nt = 0; nt < 2; ++nt) {
        const unsigned u0 = f2u(h[nt][0]), u1 = f2u(h[nt][1]);
        const unsigned u2 = f2u(h[nt][2]), u3 = f2u(h[nt][3]);
        uint2 ph, pl;
        ph.x = __builtin_amdgcn_perm(u1, u0, 0x07060302u);
        ph.y = __builtin_amdgcn_perm(u3, u2, 0x07060302u);
        const unsigned l0 = f2u(h[nt][0] - u2f(u0 & 0xFFFF0000u));
        const unsigned l1 = f2u(h[nt][1] - u2f(u1 & 0xFFFF0000u));
        const unsigned l2 = f2u(h[nt][2] - u2f(u2 & 0xFFFF0000u));
        const unsigned l3 = f2u(h[nt][3] - u2f(u3 & 0xFFFF0000u));
        pl.x = __builtin_amdgcn_perm(l1, l0, 0x07060302u);
        pl.y = __builtin_amdgcn_perm(l3, l2, 0x07060302u);
        *(uint2*)&HfH[(16 * nt + li) * 72 + joff] = ph;
        *(uint2*)&HfL[(16 * nt + li) * 72 + joff] = pl;
    }
    __syncthreads();
    {   // MLP1: wave W computes hid[m=16W+4q+rr][t] via 6 MFMA per cohort
        bf16x8 w1h[2], w1l[2];
#pragma unroll
        for (int kt = 0; kt < 2; ++kt) {
            frag_cast a, b;
            a.i4 = wfrag[(72 + W * 2 + kt) * 64 + lane];
            b.i4 = wfrag[(80 + W * 2 + kt) * 64 + lane];
            w1h[kt] = a.h8; w1l[kt] = b.h8;
        }
        const f32x4 bb1 = *(const f32x4*)&b1[joff];
#pragma unroll
        for (int nt = 0; nt < 2; ++nt) {
            const int t = 16 * nt + li;
            const bf16x8 bh0 = *(const bf16x8*)&HfH[t * 72 + 8 * q];
            const bf16x8 bh1 = *(const bf16x8*)&HfH[t * 72 + 32 + 8 * q];
            const bf16x8 bl0 = *(const bf16x8*)&HfL[t * 72 + 8 * q];
            const bf16x8 bl1 = *(const bf16x8*)&HfL[t * 72 + 32 + 8 * q];
            f32x4 a = bb1;
            a = __builtin_amdgcn_mfma_f32_16x16x32_bf16(w1h[0], bh0, a, 0, 0, 0);
            a = __builtin_amdgcn_mfma_f32_16x16x32_bf16(w1h[1], bh1, a, 0, 0, 0);
            a = __builtin_amdgcn_mfma_f32_16x16x32_bf16(w1l[0], bh0, a, 0, 0, 0);
            a = __builtin_amdgcn_mfma_f32_16x16x32_bf16(w1l[1], bh1, a, 0, 0, 0);
            a = __builtin_amdgcn_mfma_f32_16x16x32_bf16(w1h[0], bl0, a, 0, 0, 0);
            a = __builtin_amdgcn_mfma_f32_16x16x32_bf16(w1h[1], bl1, a, 0, 0, 0);
            float4 st;
            st.x = fmaxf(a[0], 0.f); st.y = fmaxf(a[1], 0.f);
            st.z = fmaxf(a[2], 0.f); st.w = fmaxf(a[3], 0.f);
            *(float4*)&Sg[t * 68 + joff] = st;   // Hid[t][m] stride 68 (aliases Sg)
        }
    }
    __syncthreads();
    if (tid < 128) {                 // MLP2: thread (tid>>2 -> t, tid&3 -> c)
        const int tt = tid >> 2, c = tid & 3;
        float o2 = b2[c];
#pragma unroll
        for (int m4 = 0; m4 < 16; ++m4) {
            const float4 hv = *(const float4*)&Sg[tt * 68 + 4 * m4];
            const float4 wv = *(const float4*)&W2[c * HH + 4 * m4];
            o2 += hv.x * wv.x + hv.y * wv.y + hv.z * wv.z + hv.w * wv.w;
        }
        out[(size_t)(T0 + tt) * 4 + c] = o2;     // 512B contiguous
    }
}

extern "C" void kernel_launch(void* const* d_in, const int* in_sizes, int n_in,
                              void* d_out, int out_size, void* d_ws, size_t ws_size,
                              hipStream_t stream) {
    const float* emb  = (const float*)d_in[0];
    const float* W_ih = (const float*)d_in[1];
    const float* W_hh = (const float*)d_in[2];
    const float* b_ih = (const float*)d_in[3];
    const float* b_hh = (const float*)d_in[4];
    const float* W1   = (const float*)d_in[5];
    const float* b1   = (const float*)d_in[6];
    const float* W2   = (const float*)d_in[7];
    const float* b2   = (const float*)d_in[8];
    const int*   dn   = (const int*)d_in[9];

    int4v* wfrag = (int4v*)d_ws;     // 88 frags x 64 lanes x 16B = 90 KB
    float* o = (float*)d_out;

    prep_kernel<<<88, 64, 0, stream>>>(W_ih, W_hh, W1, wfrag);
    gru_kernel<<<NT / TPB, 256, 0, stream>>>(emb, wfrag, b_ih, b_hh,
                                             b1, W2, b2, dn, o);
}

// Round 2
// 112.423 us; speedup vs baseline: 1.0084x; 1.0061x over previous
//
#include <hip/hip_runtime.h>

#define NT 32768
#define DI 36
#define HH 64
#define LH 20
#define TPB 64            // timesteps per block; each wave owns a private 16-t cohort
#define NROW 83           // staged emb rows = TPB + LH - 1
#define SGS 196           // Sg row stride (floats), odd 16B-granule coeff (49)
#define EMBS 40           // Emb row stride (ushorts): 80B = 5 granules (odd)

#define NLOG2E -1.4426950408889634f   // r/z pre-scale: sigmoid(x)=rcp(1+exp2(-x*log2e))
#define TLOG2E 2.8853900817779268f    // n pre-scale: tanh(x)=1-2*rcp(1+exp2(2x*log2e))

// shared memory map (bytes):
//   [0, 65072)        Sg: float[83][196] gi slices (fp32), j-quarter per wave
//   [65072, 78352)    UNION (disjoint lifetimes):
//                       phase 0/1: EmbH[83][40] + EmbL[83][40] ushort (13280B)
//                       phase 2/3: Hb[4 waves][16][72] ushort, WAVE-PRIVATE
//                                  h transpose buffers (9216B) - no barriers
//   [78352, 78608)    sfirst[64]
#define UNION_OFF  65072
#define SFIRST_OFF 78352
#define SMEM_BYTES 78608   // x2 = 157216 <= 160KB -> 2 blocks/CU (8 waves/CU)

typedef __attribute__((ext_vector_type(8))) short bf16x8;
typedef __attribute__((ext_vector_type(4))) float f32x4;
typedef __attribute__((ext_vector_type(4))) int int4v;
union frag_cast { int4v i4; bf16x8 h8; };

__device__ __forceinline__ unsigned f2u(float f) { union { float f; unsigned u; } x; x.f = f; return x.u; }
__device__ __forceinline__ float u2f(unsigned u) { union { float f; unsigned u; } x; x.u = u; return x.f; }
__device__ __forceinline__ unsigned short f2bf_rne(float f) {
    union { float f; unsigned u; } x; x.f = f;
    unsigned r = x.u + 0x7FFFu + ((x.u >> 16) & 1u);
    return (unsigned short)(r >> 16);
}

// Prep: pre-packed A-fragments, coalesced-consumable by gru.
// frags 0..23: W_ih hi (trunc, scaled) | 24..47: W_ih lo | 48..71: W_hh hi (RNE, scaled)
// frags 72..79: W1 hi (trunc) | 80..87: W1 lo
// A-frag convention: lane l holds A[m=16mt+(l&15)][k=32kt+8(l>>4)+jj].
__global__ __launch_bounds__(64) void prep_kernel(
    const float* __restrict__ W_ih, const float* __restrict__ W_hh,
    const float* __restrict__ W1, int4v* __restrict__ wfrag)
{
    const int b = (int)blockIdx.x;         // 0..87
    const int l = (int)threadIdx.x;
    unsigned short e[8];
    if (b < 72) {
        const int set = b / 24, fb = b % 24;
        const int mt = fb >> 1, kt = fb & 1;
        const int m = mt * 16 + (l & 15);  // j row 0..191
        const float sc = ((mt >> 2) < 2) ? NLOG2E : TLOG2E;
        const int k0 = kt * 32 + (l >> 4) * 8;
#pragma unroll
        for (int jj = 0; jj < 8; ++jj) {
            const int k = k0 + jj;
            if (set == 2) {
                e[jj] = f2bf_rne(W_hh[(size_t)m * HH + k] * sc);
            } else {
                const float v = (k < DI) ? W_ih[(size_t)m * DI + k] * sc : 0.f;
                const unsigned u = f2u(v);
                if (set == 0) e[jj] = (unsigned short)(u >> 16);   // trunc hi
                else          e[jj] = (unsigned short)(f2u(v - u2f(u & 0xFFFF0000u)) >> 16);
            }
        }
    } else {
        const int bb = b - 72;             // 0..15
        const bool is_lo = bb >= 8;
        const int f = bb & 7;
        const int mt = f >> 1, kt = f & 1;
        const int m = mt * 16 + (l & 15);  // 0..63
        const int k0 = kt * 32 + (l >> 4) * 8;
#pragma unroll
        for (int jj = 0; jj < 8; ++jj) {
            const float v = W1[(size_t)m * HH + k0 + jj];
            const unsigned u = f2u(v);
            if (!is_lo) e[jj] = (unsigned short)(u >> 16);         // trunc hi
            else        e[jj] = (unsigned short)(f2u(v - u2f(u & 0xFFFF0000u)) >> 16);
        }
    }
    int4v p;
    p.x = e[0] | ((unsigned)e[1] << 16); p.y = e[2] | ((unsigned)e[3] << 16);
    p.z = e[4] | ((unsigned)e[5] << 16); p.w = e[6] | ((unsigned)e[7] << 16);
    wfrag[b * 64 + l] = p;
}

// Fused kernel: 512 blocks x 256 thr (4 waves), 64 timesteps/block.
// Phase 1: cooperative gi-GEMM (j-quarter per wave) -> Sg LDS, 6 row-tiles.
// Phase 2: BARRIER-FREE recurrence: each wave owns 16 timesteps and computes
//          the full 64-wide h via 24 MFMA/step (all W_hh frags in registers);
//          h transpose through a wave-private LDS buffer (same-wave FIFO).
// Phase 3: per-wave MLP1 via MFMA (h hi/lo exact), MLP2 in-register + shfl.
__global__ __launch_bounds__(256, 2) void gru_kernel(
    const float* __restrict__ emb, const int4v* __restrict__ wfrag,
    const float* __restrict__ b_ih, const float* __restrict__ b_hh,
    const float* __restrict__ b1, const float* __restrict__ W2,
    const float* __restrict__ b2, const int* __restrict__ dones,
    float* __restrict__ out)
{
    __shared__ __align__(16) char SMEM[SMEM_BYTES];
    float* const Sg = (float*)SMEM;
    unsigned short* const EmbH = (unsigned short*)(SMEM + UNION_OFF);  // [83][40]
    unsigned short* const EmbL = EmbH + NROW * EMBS;
    unsigned short* const Hb   = (unsigned short*)(SMEM + UNION_OFF);  // [4][16][72]
    int* const sfirst = (int*)(SMEM + SFIRST_OFF);

    const int tid = threadIdx.x;
    const int lane = tid & 63;
    const int W = tid >> 6;          // wave id = cohort owner (t = 16W..16W+15)
    const int li = lane & 15;        // t within cohort (MFMA col)
    const int q = lane >> 4;         // quad
    const int blk = ((int)blockIdx.x & 7) * 64 + ((int)blockIdx.x >> 3);
    const int T0 = blk * TPB;

    // ---- Phase 0: zero Emb staging (pad cols 36..39 must be 0), window starts ----
    {
        int4v* z = (int4v*)EmbH;
        for (int i = tid; i < 830; i += 256) z[i] = int4v{0, 0, 0, 0};
    }
    if (tid < TPB) {                 // window start: dones[t-19..t-1] only
        const int tt = T0 + tid;
        int lo = tt - (LH - 1); if (lo < 0) lo = 0;
        int ws = lo;
        for (int j = lo; j < tt; ++j)
            ws = (dones[j] != 0) ? (j + 1) : ws;
        sfirst[tid] = ws - (tt - (LH - 1));
    }
    __syncthreads();
    for (int i = tid; i < NROW * DI; i += 256) {   // fill rows 0..82
        const int r = i / DI, c = i % DI;
        int tt = T0 - (LH - 1) + r; tt = tt < 0 ? 0 : tt;
        const float v = emb[(size_t)tt * DI + c];
        const unsigned u = f2u(v);
        EmbH[r * EMBS + c] = (unsigned short)(u >> 16);
        EmbL[r * EMBS + c] = (unsigned short)(f2u(v - u2f(u & 0xFFFF0000u)) >> 16);
    }

    // ---- W_ih fragments for phase 1 (wave W -> j-tiles mt=4g+W) ----
    bf16x8 aih[3][2], ail[3][2];
#pragma unroll
    for (int g = 0; g < 3; ++g)
#pragma unroll
        for (int kt = 0; kt < 2; ++kt) {
            const int fb = (4 * g + W) * 2 + kt;
            frag_cast a, b;
            a.i4 = wfrag[(0 * 24 + fb) * 64 + lane];
            b.i4 = wfrag[(1 * 24 + fb) * 64 + lane];
            aih[g][kt] = a.h8; ail[g][kt] = b.h8;
        }

    const int joff = 16 * W + 4 * q; // phase-1 j' base within each gate
    f32x4 biasI[3];                  // gi-GEMM acc init = (b_ih + b_hh_rz) * sc
#pragma unroll
    for (int g = 0; g < 3; ++g) {
        const float sc = (g < 2) ? NLOG2E : TLOG2E;
        const f32x4 bi = *(const f32x4*)&b_ih[64 * g + joff];
        if (g < 2) {
            const f32x4 bh = *(const f32x4*)&b_hh[64 * g + joff];
#pragma unroll
            for (int rr = 0; rr < 4; ++rr) biasI[g][rr] = (bi[rr] + bh[rr]) * sc;
        } else {
#pragma unroll
            for (int rr = 0; rr < 4; ++rr) biasI[g][rr] = bi[rr] * sc;
        }
    }
    __syncthreads();                 // Emb staged

    // ---- Phase 1: gi-GEMM -> Sg. Row-tiles {0,16,32,48,64,67}; tile 5
    //      rewrites rows 67..79 bit-identically (same wave, same cols).
    //      kt=1 B-frag: only q==0 lanes carry real data (k=32..39). ----
#pragma unroll
    for (int rt = 0; rt < 6; ++rt) {
        const int row0 = (rt == 5) ? 67 : 16 * rt;
        const int row = row0 + li;
        bf16x8 ebh0 = *(const bf16x8*)&EmbH[row * EMBS + 8 * q];
        bf16x8 ebl0 = *(const bf16x8*)&EmbL[row * EMBS + 8 * q];
        bf16x8 ebh1 = bf16x8{0, 0, 0, 0, 0, 0, 0, 0};
        bf16x8 ebl1 = bf16x8{0, 0, 0, 0, 0, 0, 0, 0};
        if (q == 0) {
            ebh1 = *(const bf16x8*)&EmbH[row * EMBS + 32];
            ebl1 = *(const bf16x8*)&EmbL[row * EMBS + 32];
        }
#pragma unroll
        for (int g = 0; g < 3; ++g) {
            f32x4 a = biasI[g];
            a = __builtin_amdgcn_mfma_f32_16x16x32_bf16(aih[g][0], ebh0, a, 0, 0, 0);
            a = __builtin_amdgcn_mfma_f32_16x16x32_bf16(aih[g][1], ebh1, a, 0, 0, 0);
            a = __builtin_amdgcn_mfma_f32_16x16x32_bf16(ail[g][0], ebh0, a, 0, 0, 0);
            a = __builtin_amdgcn_mfma_f32_16x16x32_bf16(ail[g][1], ebh1, a, 0, 0, 0);
            a = __builtin_amdgcn_mfma_f32_16x16x32_bf16(aih[g][0], ebl0, a, 0, 0, 0);
            a = __builtin_amdgcn_mfma_f32_16x16x32_bf16(aih[g][1], ebl1, a, 0, 0, 0);
            *(f32x4*)&Sg[row * SGS + 64 * g + joff] = a;
        }
    }
    __syncthreads();                 // Sg complete; Emb dead (Hb aliases Emb)

    // ---- W_hh fragments: the full 3x4x2 set per wave (96 VGPR) ----
    bf16x8 whh[3][4][2];
#pragma unroll
    for (int g = 0; g < 3; ++g)
#pragma unroll
        for (int mt = 0; mt < 4; ++mt)
#pragma unroll
            for (int kt = 0; kt < 2; ++kt) {
                frag_cast c;
                c.i4 = wfrag[(48 + (4 * g + mt) * 2 + kt) * 64 + lane];
                whh[g][mt][kt] = c.h8;
            }
    f32x4 bnv4[4];                   // n-gate step init = 2*log2e * b_hh_n
#pragma unroll
    for (int mt = 0; mt < 4; ++mt) {
        const f32x4 b = *(const f32x4*)&b_hh[128 + 16 * mt + 4 * q];
#pragma unroll
        for (int rr = 0; rr < 4; ++rr) bnv4[mt][rr] = b[rr] * TLOG2E;
    }
    const int sfr = sfirst[16 * W + li];
    unsigned short* const Hbw = Hb + W * 1152;   // wave-private [16][72]

    // ---- Phase 2: barrier-free recurrence; wave computes full h for its cohort ----
    float h[4][4];
    {   // s = 0 (h=0: no MFMA), seed transpose buffer
        const float* gp = Sg + (16 * W + li) * SGS;
        const bool valid = (0 >= sfr);
#pragma unroll
        for (int mt = 0; mt < 4; ++mt) {
            const f32x4 aR = *(const f32x4*)(gp + 16 * mt + 4 * q);
            const f32x4 aZ = *(const f32x4*)(gp + 64 + 16 * mt + 4 * q);
            const f32x4 gI = *(const f32x4*)(gp + 128 + 16 * mt + 4 * q);
#pragma unroll
            for (int rr = 0; rr < 4; ++rr) {
                const float r  = __builtin_amdgcn_rcpf(1.f + __builtin_amdgcn_exp2f(aR[rr]));
                const float z  = __builtin_amdgcn_rcpf(1.f + __builtin_amdgcn_exp2f(aZ[rr]));
                const float nc = 1.f - 2.f * __builtin_amdgcn_rcpf(1.f + __builtin_amdgcn_exp2f(gI[rr] + r * bnv4[mt][rr]));
                h[mt][rr] = valid ? fmaf(z, 0.f - nc, nc) : 0.f;
            }
            uint2 ph;
            ph.x = __builtin_amdgcn_perm(f2u(h[mt][1]), f2u(h[mt][0]), 0x07060302u);
            ph.y = __builtin_amdgcn_perm(f2u(h[mt][3]), f2u(h[mt][2]), 0x07060302u);
            *(uint2*)&Hbw[li * 72 + 16 * mt + 4 * q] = ph;
        }
    }

#pragma unroll 1
    for (int s = 1; s < LH; ++s) {
        // read h_{s-1} as B-fragments (same-wave FIFO vs the writes above)
        const bf16x8 bh0 = *(const bf16x8*)&Hbw[li * 72 + 8 * q];
        const bf16x8 bh1 = *(const bf16x8*)&Hbw[li * 72 + 32 + 8 * q];
        const float* gp = Sg + (16 * W + li + s) * SGS;
        f32x4 aR[4], aZ[4], aN[4], gI[4];
#pragma unroll
        for (int mt = 0; mt < 4; ++mt) {
            aR[mt] = *(const f32x4*)(gp + 16 * mt + 4 * q);
            aZ[mt] = *(const f32x4*)(gp + 64 + 16 * mt + 4 * q);
            gI[mt] = *(const f32x4*)(gp + 128 + 16 * mt + 4 * q);
            aN[mt] = bnv4[mt];
        }
#pragma unroll
        for (int mt = 0; mt < 4; ++mt) {
            aR[mt] = __builtin_amdgcn_mfma_f32_16x16x32_bf16(whh[0][mt][0], bh0, aR[mt], 0, 0, 0);
            aR[mt] = __builtin_amdgcn_mfma_f32_16x16x32_bf16(whh[0][mt][1], bh1, aR[mt], 0, 0, 0);
            aZ[mt] = __builtin_amdgcn_mfma_f32_16x16x32_bf16(whh[1][mt][0], bh0, aZ[mt], 0, 0, 0);
            aZ[mt] = __builtin_amdgcn_mfma_f32_16x16x32_bf16(whh[1][mt][1], bh1, aZ[mt], 0, 0, 0);
            aN[mt] = __builtin_amdgcn_mfma_f32_16x16x32_bf16(whh[2][mt][0], bh0, aN[mt], 0, 0, 0);
            aN[mt] = __builtin_amdgcn_mfma_f32_16x16x32_bf16(whh[2][mt][1], bh1, aN[mt], 0, 0, 0);
        }
        const bool valid = (s >= sfr);
#pragma unroll
        for (int mt = 0; mt < 4; ++mt) {
#pragma unroll
            for (int rr = 0; rr < 4; ++rr) {
                const float r  = __builtin_amdgcn_rcpf(1.f + __builtin_amdgcn_exp2f(aR[mt][rr]));
                const float z  = __builtin_amdgcn_rcpf(1.f + __builtin_amdgcn_exp2f(aZ[mt][rr]));
                const float nc = 1.f - 2.f * __builtin_amdgcn_rcpf(1.f + __builtin_amdgcn_exp2f(gI[mt][rr] + r * aN[mt][rr]));
                const float hn = fmaf(z, h[mt][rr] - nc, nc);
                h[mt][rr] = valid ? hn : h[mt][rr];
            }
            if (s != LH - 1) {       // overwrite same buffer: reads above already landed
                uint2 ph;
                ph.x = __builtin_amdgcn_perm(f2u(h[mt][1]), f2u(h[mt][0]), 0x07060302u);
                ph.y = __builtin_amdgcn_perm(f2u(h[mt][3]), f2u(h[mt][2]), 0x07060302u);
                *(uint2*)&Hbw[li * 72 + 16 * mt + 4 * q] = ph;
            }
        }
    }

    // ---- Phase 3 (wave-private): MLP1 via MFMA (h hi/lo exact), MLP2 in-reg ----
    bf16x8 w1h[4][2], w1l[4][2];
#pragma unroll
    for (int mt = 0; mt < 4; ++mt)
#pragma unroll
        for (int kt = 0; kt < 2; ++kt) {
            frag_cast a, b;
            a.i4 = wfrag[(72 + mt * 2 + kt) * 64 + lane];
            b.i4 = wfrag[(80 + mt * 2 + kt) * 64 + lane];
            w1h[mt][kt] = a.h8; w1l[mt][kt] = b.h8;
        }
    // hi plane into Hbw, read fragments
#pragma unroll
    for (int mt = 0; mt < 4; ++mt) {
        uint2 ph;
        ph.x = __builtin_amdgcn_perm(f2u(h[mt][1]), f2u(h[mt][0]), 0x07060302u);
        ph.y = __builtin_amdgcn_perm(f2u(h[mt][3]), f2u(h[mt][2]), 0x07060302u);
        *(uint2*)&Hbw[li * 72 + 16 * mt + 4 * q] = ph;
    }
    const bf16x8 bh0 = *(const bf16x8*)&Hbw[li * 72 + 8 * q];
    const bf16x8 bh1 = *(const bf16x8*)&Hbw[li * 72 + 32 + 8 * q];
    // lo plane (overwrites hi; same-wave FIFO keeps read->write order)
#pragma unroll
    for (int mt = 0; mt < 4; ++mt) {
        const unsigned u0 = f2u(h[mt][0]), u1 = f2u(h[mt][1]);
        const unsigned u2 = f2u(h[mt][2]), u3 = f2u(h[mt][3]);
        const unsigned l0 = f2u(h[mt][0] - u2f(u0 & 0xFFFF0000u));
        const unsigned l1 = f2u(h[mt][1] - u2f(u1 & 0xFFFF0000u));
        const unsigned l2 = f2u(h[mt][2] - u2f(u2 & 0xFFFF0000u));
        const unsigned l3 = f2u(h[mt][3] - u2f(u3 & 0xFFFF0000u));
        uint2 pl;
        pl.x = __builtin_amdgcn_perm(l1, l0, 0x07060302u);
        pl.y = __builtin_amdgcn_perm(l3, l2, 0x07060302u);
        *(uint2*)&Hbw[li * 72 + 16 * mt + 4 * q] = pl;
    }
    const bf16x8 bl0 = *(const bf16x8*)&Hbw[li * 72 + 8 * q];
    const bf16x8 bl1 = *(const bf16x8*)&Hbw[li * 72 + 32 + 8 * q];

    float p0 = 0.f, p1 = 0.f, p2 = 0.f, p3 = 0.f;
#pragma unroll
    for (int mt = 0; mt < 4; ++mt) {
        f32x4 a = *(const f32x4*)&b1[16 * mt + 4 * q];
        a = __builtin_amdgcn_mfma_f32_16x16x32_bf16(w1h[mt][0], bh0, a, 0, 0, 0);
        a = __builtin_amdgcn_mfma_f32_16x16x32_bf16(w1h[mt][1], bh1, a, 0, 0, 0);
        a = __builtin_amdgcn_mfma_f32_16x16x32_bf16(w1l[mt][0], bh0, a, 0, 0, 0);
        a = __builtin_amdgcn_mfma_f32_16x16x32_bf16(w1l[mt][1], bh1, a, 0, 0, 0);
        a = __builtin_amdgcn_mfma_f32_16x16x32_bf16(w1h[mt][0], bl0, a, 0, 0, 0);
        a = __builtin_amdgcn_mfma_f32_16x16x32_bf16(w1h[mt][1], bl1, a, 0, 0, 0);
        const float h0 = fmaxf(a[0], 0.f), h1 = fmaxf(a[1], 0.f);
        const float h2 = fmaxf(a[2], 0.f), h3 = fmaxf(a[3], 0.f);
        // MLP2 partials: this lane's m-slice (m = 16mt+4q+rr) for all 4 c
        const f32x4 w0 = *(const f32x4*)&W2[0 * HH + 16 * mt + 4 * q];
        const f32x4 w1 = *(const f32x4*)&W2[1 * HH + 16 * mt + 4 * q];
        const f32x4 w2 = *(const f32x4*)&W2[2 * HH + 16 * mt + 4 * q];
        const f32x4 w3 = *(const f32x4*)&W2[3 * HH + 16 * mt + 4 * q];
        p0 += h0 * w0[0] + h1 * w0[1] + h2 * w0[2] + h3 * w0[3];
        p1 += h0 * w1[0] + h1 * w1[1] + h2 * w1[2] + h3 * w1[3];
        p2 += h0 * w2[0] + h1 * w2[1] + h2 * w2[2] + h3 * w2[3];
        p3 += h0 * w3[0] + h1 * w3[1] + h2 * w3[2] + h3 * w3[3];
    }
    // reduce the m-slices across the 4 q-lanes (li, li+16, li+32, li+48)
    p0 += __shfl_xor(p0, 16); p0 += __shfl_xor(p0, 32);
    p1 += __shfl_xor(p1, 16); p1 += __shfl_xor(p1, 32);
    p2 += __shfl_xor(p2, 16); p2 += __shfl_xor(p2, 32);
    p3 += __shfl_xor(p3, 16); p3 += __shfl_xor(p3, 32);
    const float pv = (q == 0) ? p0 : (q == 1) ? p1 : (q == 2) ? p2 : p3;
    out[(size_t)(T0 + 16 * W + li) * 4 + q] = pv + b2[q];
}

extern "C" void kernel_launch(void* const* d_in, const int* in_sizes, int n_in,
                              void* d_out, int out_size, void* d_ws, size_t ws_size,
                              hipStream_t stream) {
    const float* emb  = (const float*)d_in[0];
    const float* W_ih = (const float*)d_in[1];
    const float* W_hh = (const float*)d_in[2];
    const float* b_ih = (const float*)d_in[3];
    const float* b_hh = (const float*)d_in[4];
    const float* W1   = (const float*)d_in[5];
    const float* b1   = (const float*)d_in[6];
    const float* W2   = (const float*)d_in[7];
    const float* b2   = (const float*)d_in[8];
    const int*   dn   = (const int*)d_in[9];

    int4v* wfrag = (int4v*)d_ws;     // 88 frags x 64 lanes x 16B = 90 KB
    float* o = (float*)d_out;

    prep_kernel<<<88, 64, 0, stream>>>(W_ih, W_hh, W1, wfrag);
    gru_kernel<<<NT / TPB, 256, 0, stream>>>(emb, wfrag, b_ih, b_hh,
                                             b1, W2, b2, dn, o);
}

// Round 3
// 111.398 us; speedup vs baseline: 1.0177x; 1.0092x over previous
//
#include <hip/hip_runtime.h>

#define NT 32768
#define DI 36
#define HH 64
#define LH 20
#define TPB 64            // timesteps per block; each wave owns a private 16-t cohort
#define NROW 83           // staged emb rows = TPB + LH - 1
#define SGS 196           // Sg row stride (floats), odd 16B-granule coeff (49)
#define EMBS 40           // Emb row stride (ushorts): 80B = 5 granules (odd)

#define NLOG2E -1.4426950408889634f   // r/z pre-scale: sigmoid(x)=rcp(1+exp2(-x*log2e))
#define TLOG2E 2.8853900817779268f    // n pre-scale: tanh(x)=1-2*rcp(1+exp2(2x*log2e))

// shared memory map (bytes):
//   [0, 65072)        Sg: float[83][196] gi slices (fp32), j-quarter per wave
//   [65072, 78352)    UNION (disjoint lifetimes):
//                       phase 0/1: EmbH[83][40] + EmbL[83][40] ushort (13280B)
//                       phase 2/3: Hb[4 waves][16][72] ushort, WAVE-PRIVATE
//   [78352, 78608)    sfirst[64]
#define UNION_OFF  65072
#define SFIRST_OFF 78352
#define SMEM_BYTES 78608   // x2 = 157216 <= 160KB -> 2 blocks/CU (8 waves/CU)

typedef __attribute__((ext_vector_type(8))) short bf16x8;
typedef __attribute__((ext_vector_type(4))) float f32x4;
typedef __attribute__((ext_vector_type(4))) int int4v;
union frag_cast { int4v i4; bf16x8 h8; };

__device__ __forceinline__ unsigned f2u(float f) { union { float f; unsigned u; } x; x.f = f; return x.u; }
__device__ __forceinline__ float u2f(unsigned u) { union { float f; unsigned u; } x; x.u = u; return x.f; }
__device__ __forceinline__ unsigned short f2bf_rne(float f) {
    union { float f; unsigned u; } x; x.f = f;
    unsigned r = x.u + 0x7FFFu + ((x.u >> 16) & 1u);
    return (unsigned short)(r >> 16);
}

// GRU gate math for 4 values with 4-way batched reciprocals:
// r = 1/(1+exp2(aR)), z = 1/(1+exp2(aZ)), nc = 1-2/(1+exp2(aI + r*aN)),
// h = valid ? z*(h-nc)+nc : h.  3 rcp (instead of 12) + 27 mul per call.
__device__ __forceinline__ void gate4(const f32x4 aR, const f32x4 aZ,
                                      const f32x4 aI, const f32x4 aN,
                                      const bool valid, float* hh) {
    float dR[4], dZ[4], dN[4], rv[4], zv[4], iv[4];
#pragma unroll
    for (int e = 0; e < 4; ++e) dR[e] = 1.f + __builtin_amdgcn_exp2f(aR[e]);
#pragma unroll
    for (int e = 0; e < 4; ++e) dZ[e] = 1.f + __builtin_amdgcn_exp2f(aZ[e]);
    {
        const float pa = dR[0] * dR[1], pb = dR[2] * dR[3];
        const float rp = __builtin_amdgcn_rcpf(pa * pb);
        const float ia = rp * pb, ib = rp * pa;
        rv[0] = ia * dR[1]; rv[1] = ia * dR[0];
        rv[2] = ib * dR[3]; rv[3] = ib * dR[2];
    }
    {
        const float pa = dZ[0] * dZ[1], pb = dZ[2] * dZ[3];
        const float rp = __builtin_amdgcn_rcpf(pa * pb);
        const float ia = rp * pb, ib = rp * pa;
        zv[0] = ia * dZ[1]; zv[1] = ia * dZ[0];
        zv[2] = ib * dZ[3]; zv[3] = ib * dZ[2];
    }
#pragma unroll
    for (int e = 0; e < 4; ++e)
        dN[e] = 1.f + __builtin_amdgcn_exp2f(fmaf(rv[e], aN[e], aI[e]));
    {
        const float pa = dN[0] * dN[1], pb = dN[2] * dN[3];
        const float rp = __builtin_amdgcn_rcpf(pa * pb);
        const float ia = rp * pb, ib = rp * pa;
        iv[0] = ia * dN[1]; iv[1] = ia * dN[0];
        iv[2] = ib * dN[3]; iv[3] = ib * dN[2];
    }
#pragma unroll
    for (int e = 0; e < 4; ++e) {
        const float nc = fmaf(-2.f, iv[e], 1.f);
        const float hn = fmaf(zv[e], hh[e] - nc, nc);
        hh[e] = valid ? hn : hh[e];
    }
}

// Prep: pre-packed A-fragments, coalesced-consumable by gru.
// frags 0..23: W_ih hi (trunc, scaled) | 24..47: W_ih lo | 48..71: W_hh hi (RNE, scaled)
// frags 72..79: W1 hi (trunc) | 80..87: W1 lo
// A-frag convention: lane l holds A[m=16mt+(l&15)][k=32kt+8(l>>4)+jj].
__global__ __launch_bounds__(64) void prep_kernel(
    const float* __restrict__ W_ih, const float* __restrict__ W_hh,
    const float* __restrict__ W1, int4v* __restrict__ wfrag)
{
    const int b = (int)blockIdx.x;         // 0..87
    const int l = (int)threadIdx.x;
    unsigned short e[8];
    if (b < 72) {
        const int set = b / 24, fb = b % 24;
        const int mt = fb >> 1, kt = fb & 1;
        const int m = mt * 16 + (l & 15);  // j row 0..191
        const float sc = ((mt >> 2) < 2) ? NLOG2E : TLOG2E;
        const int k0 = kt * 32 + (l >> 4) * 8;
#pragma unroll
        for (int jj = 0; jj < 8; ++jj) {
            const int k = k0 + jj;
            if (set == 2) {
                e[jj] = f2bf_rne(W_hh[(size_t)m * HH + k] * sc);
            } else {
                const float v = (k < DI) ? W_ih[(size_t)m * DI + k] * sc : 0.f;
                const unsigned u = f2u(v);
                if (set == 0) e[jj] = (unsigned short)(u >> 16);   // trunc hi
                else          e[jj] = (unsigned short)(f2u(v - u2f(u & 0xFFFF0000u)) >> 16);
            }
        }
    } else {
        const int bb = b - 72;             // 0..15
        const bool is_lo = bb >= 8;
        const int f = bb & 7;
        const int mt = f >> 1, kt = f & 1;
        const int m = mt * 16 + (l & 15);  // 0..63
        const int k0 = kt * 32 + (l >> 4) * 8;
#pragma unroll
        for (int jj = 0; jj < 8; ++jj) {
            const float v = W1[(size_t)m * HH + k0 + jj];
            const unsigned u = f2u(v);
            if (!is_lo) e[jj] = (unsigned short)(u >> 16);         // trunc hi
            else        e[jj] = (unsigned short)(f2u(v - u2f(u & 0xFFFF0000u)) >> 16);
        }
    }
    int4v p;
    p.x = e[0] | ((unsigned)e[1] << 16); p.y = e[2] | ((unsigned)e[3] << 16);
    p.z = e[4] | ((unsigned)e[5] << 16); p.w = e[6] | ((unsigned)e[7] << 16);
    wfrag[b * 64 + l] = p;
}

// Fused kernel: 512 blocks x 256 thr (4 waves), 64 timesteps/block.
// Phase 1: cooperative gi-GEMM (j-quarter per wave) -> Sg LDS, 6 row-tiles.
// Phase 2: barrier-free recurrence, per-mt fused MFMA->gates->write with
//          gi prefetch (next step's 12 LDS reads in flight during compute)
//          and 4-way batched reciprocals (60 trans/step instead of 96).
// Phase 3: per-wave MLP1 via MFMA (h hi/lo exact), MLP2 in-register + shfl.
__global__ __launch_bounds__(256, 2) void gru_kernel(
    const float* __restrict__ emb, const int4v* __restrict__ wfrag,
    const float* __restrict__ b_ih, const float* __restrict__ b_hh,
    const float* __restrict__ b1, const float* __restrict__ W2,
    const float* __restrict__ b2, const int* __restrict__ dones,
    float* __restrict__ out)
{
    __shared__ __align__(16) char SMEM[SMEM_BYTES];
    float* const Sg = (float*)SMEM;
    unsigned short* const EmbH = (unsigned short*)(SMEM + UNION_OFF);  // [83][40]
    unsigned short* const EmbL = EmbH + NROW * EMBS;
    unsigned short* const Hb   = (unsigned short*)(SMEM + UNION_OFF);  // [4][16][72]
    int* const sfirst = (int*)(SMEM + SFIRST_OFF);

    const int tid = threadIdx.x;
    const int lane = tid & 63;
    const int W = tid >> 6;          // wave id = cohort owner (t = 16W..16W+15)
    const int li = lane & 15;        // t within cohort (MFMA col)
    const int q = lane >> 4;         // quad
    const int blk = ((int)blockIdx.x & 7) * 64 + ((int)blockIdx.x >> 3);
    const int T0 = blk * TPB;

    // ---- Phase 0: window starts (fixed-trip, pipelined loads) ----
    if (tid < TPB) {
        const int tt = T0 + tid;
        int off = (tt >= LH - 1) ? 0 : (LH - 1) - tt;   // mask rows before t=0
#pragma unroll
        for (int k = LH - 1; k >= 1; --k) {             // ascending j; last done wins
            const int j = tt - k;
            const int jj = j < 0 ? 0 : j;
            const bool d = (j >= 0) && (dones[jj] != 0);
            if (d) off = LH - k;
        }
        sfirst[tid] = off;
    }
    // ---- Emb staging: vectorized f32x4 loads, hi/lo bf16 split ----
    for (int i = tid; i < NROW * 9; i += 256) {         // 83 rows x 9 f32x4 chunks
        const int r = i / 9, c = i - r * 9;
        int tt = T0 - (LH - 1) + r; tt = tt < 0 ? 0 : tt;
        const f32x4 v = *(const f32x4*)&emb[(size_t)tt * DI + 4 * c];
        const unsigned u0 = f2u(v[0]), u1 = f2u(v[1]);
        const unsigned u2 = f2u(v[2]), u3 = f2u(v[3]);
        uint2 ph, pl;
        ph.x = __builtin_amdgcn_perm(u1, u0, 0x07060302u);
        ph.y = __builtin_amdgcn_perm(u3, u2, 0x07060302u);
        const unsigned l0 = f2u(v[0] - u2f(u0 & 0xFFFF0000u));
        const unsigned l1 = f2u(v[1] - u2f(u1 & 0xFFFF0000u));
        const unsigned l2 = f2u(v[2] - u2f(u2 & 0xFFFF0000u));
        const unsigned l3 = f2u(v[3] - u2f(u3 & 0xFFFF0000u));
        pl.x = __builtin_amdgcn_perm(l1, l0, 0x07060302u);
        pl.y = __builtin_amdgcn_perm(l3, l2, 0x07060302u);
        *(uint2*)&EmbH[r * EMBS + 4 * c] = ph;
        *(uint2*)&EmbL[r * EMBS + 4 * c] = pl;
    }
    if (tid < NROW) {               // zero pad cols 36..39 only
        const uint2 z2 = {0u, 0u};
        *(uint2*)&EmbH[tid * EMBS + DI] = z2;
        *(uint2*)&EmbL[tid * EMBS + DI] = z2;
    }

    // ---- W fragments (issued during staging): phase-1 A-frags + full W_hh ----
    bf16x8 aih[3][2], ail[3][2];
#pragma unroll
    for (int g = 0; g < 3; ++g)
#pragma unroll
        for (int kt = 0; kt < 2; ++kt) {
            const int fb = (4 * g + W) * 2 + kt;
            frag_cast a, b;
            a.i4 = wfrag[(0 * 24 + fb) * 64 + lane];
            b.i4 = wfrag[(1 * 24 + fb) * 64 + lane];
            aih[g][kt] = a.h8; ail[g][kt] = b.h8;
        }
    bf16x8 whh[3][4][2];
#pragma unroll
    for (int g = 0; g < 3; ++g)
#pragma unroll
        for (int mt = 0; mt < 4; ++mt)
#pragma unroll
            for (int kt = 0; kt < 2; ++kt) {
                frag_cast c;
                c.i4 = wfrag[(48 + (4 * g + mt) * 2 + kt) * 64 + lane];
                whh[g][mt][kt] = c.h8;
            }

    const int joff = 16 * W + 4 * q; // phase-1 j' base within each gate
    f32x4 biasI[3];                  // gi-GEMM acc init = (b_ih + b_hh_rz) * sc
#pragma unroll
    for (int g = 0; g < 3; ++g) {
        const float sc = (g < 2) ? NLOG2E : TLOG2E;
        const f32x4 bi = *(const f32x4*)&b_ih[64 * g + joff];
        if (g < 2) {
            const f32x4 bh = *(const f32x4*)&b_hh[64 * g + joff];
#pragma unroll
            for (int rr = 0; rr < 4; ++rr) biasI[g][rr] = (bi[rr] + bh[rr]) * sc;
        } else {
#pragma unroll
            for (int rr = 0; rr < 4; ++rr) biasI[g][rr] = bi[rr] * sc;
        }
    }
    __syncthreads();                 // Emb staged, sfirst ready

    // ---- Phase 1: gi-GEMM -> Sg. Row-tiles {0,16,32,48,64,67}; tile 5
    //      rewrites rows 67..79 bit-identically (same wave, same cols).
    //      kt=1 B-frag: only q==0 lanes carry real data (k=32..39). ----
#pragma unroll
    for (int rt = 0; rt < 6; ++rt) {
        const int row0 = (rt == 5) ? 67 : 16 * rt;
        const int row = row0 + li;
        bf16x8 ebh0 = *(const bf16x8*)&EmbH[row * EMBS + 8 * q];
        bf16x8 ebl0 = *(const bf16x8*)&EmbL[row * EMBS + 8 * q];
        bf16x8 ebh1 = bf16x8{0, 0, 0, 0, 0, 0, 0, 0};
        bf16x8 ebl1 = bf16x8{0, 0, 0, 0, 0, 0, 0, 0};
        if (q == 0) {
            ebh1 = *(const bf16x8*)&EmbH[row * EMBS + 32];
            ebl1 = *(const bf16x8*)&EmbL[row * EMBS + 32];
        }
#pragma unroll
        for (int g = 0; g < 3; ++g) {
            f32x4 a = biasI[g];
            a = __builtin_amdgcn_mfma_f32_16x16x32_bf16(aih[g][0], ebh0, a, 0, 0, 0);
            a = __builtin_amdgcn_mfma_f32_16x16x32_bf16(aih[g][1], ebh1, a, 0, 0, 0);
            a = __builtin_amdgcn_mfma_f32_16x16x32_bf16(ail[g][0], ebh0, a, 0, 0, 0);
            a = __builtin_amdgcn_mfma_f32_16x16x32_bf16(ail[g][1], ebh1, a, 0, 0, 0);
            a = __builtin_amdgcn_mfma_f32_16x16x32_bf16(aih[g][0], ebl0, a, 0, 0, 0);
            a = __builtin_amdgcn_mfma_f32_16x16x32_bf16(aih[g][1], ebl1, a, 0, 0, 0);
            *(f32x4*)&Sg[row * SGS + 64 * g + joff] = a;
        }
    }
    __syncthreads();                 // Sg complete; Emb dead (Hb aliases Emb)

    f32x4 bnv4[4];                   // n-gate step init = 2*log2e * b_hh_n
#pragma unroll
    for (int mt = 0; mt < 4; ++mt) {
        const f32x4 b = *(const f32x4*)&b_hh[128 + 16 * mt + 4 * q];
#pragma unroll
        for (int rr = 0; rr < 4; ++rr) bnv4[mt][rr] = b[rr] * TLOG2E;
    }
    const int sfr = sfirst[16 * W + li];
    unsigned short* const Hbw = Hb + W * 1152;   // wave-private [16][72]

    // ---- Phase 2: barrier-free recurrence; per-mt fused, prefetched ----
    float h[4][4];
    f32x4 gvR[4], gvZ[4], gvI[4];    // gi prefetch for next step
    {   // s = 0 (h=0: no MFMA), seed transpose buffer + prefetch s=1
        const float* gp = Sg + (16 * W + li) * SGS;
        const bool valid = (0 >= sfr);
#pragma unroll
        for (int mt = 0; mt < 4; ++mt) {
            const f32x4 aR = *(const f32x4*)(gp + 16 * mt + 4 * q);
            const f32x4 aZ = *(const f32x4*)(gp + 64 + 16 * mt + 4 * q);
            const f32x4 aI = *(const f32x4*)(gp + 128 + 16 * mt + 4 * q);
            h[mt][0] = 0.f; h[mt][1] = 0.f; h[mt][2] = 0.f; h[mt][3] = 0.f;
            gate4(aR, aZ, aI, bnv4[mt], valid, h[mt]);
            uint2 ph;
            ph.x = __builtin_amdgcn_perm(f2u(h[mt][1]), f2u(h[mt][0]), 0x07060302u);
            ph.y = __builtin_amdgcn_perm(f2u(h[mt][3]), f2u(h[mt][2]), 0x07060302u);
            *(uint2*)&Hbw[li * 72 + 16 * mt + 4 * q] = ph;
        }
        const float* gq = Sg + (16 * W + li + 1) * SGS;
#pragma unroll
        for (int mt = 0; mt < 4; ++mt) {
            gvR[mt] = *(const f32x4*)(gq + 16 * mt + 4 * q);
            gvZ[mt] = *(const f32x4*)(gq + 64 + 16 * mt + 4 * q);
            gvI[mt] = *(const f32x4*)(gq + 128 + 16 * mt + 4 * q);
        }
    }

#pragma unroll 2
    for (int s = 1; s < LH; ++s) {
        // read h_{s-1} as B-fragments (same-wave FIFO vs the writes above)
        const bf16x8 bh0 = *(const bf16x8*)&Hbw[li * 72 + 8 * q];
        const bf16x8 bh1 = *(const bf16x8*)&Hbw[li * 72 + 32 + 8 * q];
        f32x4 aR[4], aZ[4], aN[4], aI[4];
#pragma unroll
        for (int mt = 0; mt < 4; ++mt) {
            aR[mt] = gvR[mt]; aZ[mt] = gvZ[mt]; aI[mt] = gvI[mt]; aN[mt] = bnv4[mt];
        }
        {   // prefetch s+1's gi (row clamped; final-iter values unused)
            int rrow = 16 * W + li + s + 1; rrow = rrow > NROW - 1 ? NROW - 1 : rrow;
            const float* gq = Sg + rrow * SGS;
#pragma unroll
            for (int mt = 0; mt < 4; ++mt) {
                gvR[mt] = *(const f32x4*)(gq + 16 * mt + 4 * q);
                gvZ[mt] = *(const f32x4*)(gq + 64 + 16 * mt + 4 * q);
                gvI[mt] = *(const f32x4*)(gq + 128 + 16 * mt + 4 * q);
            }
        }
        const bool valid = (s >= sfr);
#pragma unroll
        for (int mt = 0; mt < 4; ++mt) {
            aR[mt] = __builtin_amdgcn_mfma_f32_16x16x32_bf16(whh[0][mt][0], bh0, aR[mt], 0, 0, 0);
            aR[mt] = __builtin_amdgcn_mfma_f32_16x16x32_bf16(whh[0][mt][1], bh1, aR[mt], 0, 0, 0);
            aZ[mt] = __builtin_amdgcn_mfma_f32_16x16x32_bf16(whh[1][mt][0], bh0, aZ[mt], 0, 0, 0);
            aZ[mt] = __builtin_amdgcn_mfma_f32_16x16x32_bf16(whh[1][mt][1], bh1, aZ[mt], 0, 0, 0);
            aN[mt] = __builtin_amdgcn_mfma_f32_16x16x32_bf16(whh[2][mt][0], bh0, aN[mt], 0, 0, 0);
            aN[mt] = __builtin_amdgcn_mfma_f32_16x16x32_bf16(whh[2][mt][1], bh1, aN[mt], 0, 0, 0);
            gate4(aR[mt], aZ[mt], aI[mt], aN[mt], valid, h[mt]);
            if (s != LH - 1) {       // overwrite same buffer: reads above landed
                uint2 ph;
                ph.x = __builtin_amdgcn_perm(f2u(h[mt][1]), f2u(h[mt][0]), 0x07060302u);
                ph.y = __builtin_amdgcn_perm(f2u(h[mt][3]), f2u(h[mt][2]), 0x07060302u);
                *(uint2*)&Hbw[li * 72 + 16 * mt + 4 * q] = ph;
            }
        }
    }

    // ---- Phase 3 (wave-private): MLP1 via MFMA (h hi/lo exact), MLP2 in-reg ----
    bf16x8 w1h[4][2], w1l[4][2];
#pragma unroll
    for (int mt = 0; mt < 4; ++mt)
#pragma unroll
        for (int kt = 0; kt < 2; ++kt) {
            frag_cast a, b;
            a.i4 = wfrag[(72 + mt * 2 + kt) * 64 + lane];
            b.i4 = wfrag[(80 + mt * 2 + kt) * 64 + lane];
            w1h[mt][kt] = a.h8; w1l[mt][kt] = b.h8;
        }
    // hi plane into Hbw, read fragments
#pragma unroll
    for (int mt = 0; mt < 4; ++mt) {
        uint2 ph;
        ph.x = __builtin_amdgcn_perm(f2u(h[mt][1]), f2u(h[mt][0]), 0x07060302u);
        ph.y = __builtin_amdgcn_perm(f2u(h[mt][3]), f2u(h[mt][2]), 0x07060302u);
        *(uint2*)&Hbw[li * 72 + 16 * mt + 4 * q] = ph;
    }
    const bf16x8 bh0 = *(const bf16x8*)&Hbw[li * 72 + 8 * q];
    const bf16x8 bh1 = *(const bf16x8*)&Hbw[li * 72 + 32 + 8 * q];
    // lo plane (overwrites hi; same-wave FIFO keeps read->write order)
#pragma unroll
    for (int mt = 0; mt < 4; ++mt) {
        const unsigned u0 = f2u(h[mt][0]), u1 = f2u(h[mt][1]);
        const unsigned u2 = f2u(h[mt][2]), u3 = f2u(h[mt][3]);
        const unsigned l0 = f2u(h[mt][0] - u2f(u0 & 0xFFFF0000u));
        const unsigned l1 = f2u(h[mt][1] - u2f(u1 & 0xFFFF0000u));
        const unsigned l2 = f2u(h[mt][2] - u2f(u2 & 0xFFFF0000u));
        const unsigned l3 = f2u(h[mt][3] - u2f(u3 & 0xFFFF0000u));
        uint2 pl;
        pl.x = __builtin_amdgcn_perm(l1, l0, 0x07060302u);
        pl.y = __builtin_amdgcn_perm(l3, l2, 0x07060302u);
        *(uint2*)&Hbw[li * 72 + 16 * mt + 4 * q] = pl;
    }
    const bf16x8 bl0 = *(const bf16x8*)&Hbw[li * 72 + 8 * q];
    const bf16x8 bl1 = *(const bf16x8*)&Hbw[li * 72 + 32 + 8 * q];

    float p0 = 0.f, p1 = 0.f, p2 = 0.f, p3 = 0.f;
#pragma unroll
    for (int mt = 0; mt < 4; ++mt) {
        f32x4 a = *(const f32x4*)&b1[16 * mt + 4 * q];
        a = __builtin_amdgcn_mfma_f32_16x16x32_bf16(w1h[mt][0], bh0, a, 0, 0, 0);
        a = __builtin_amdgcn_mfma_f32_16x16x32_bf16(w1h[mt][1], bh1, a, 0, 0, 0);
        a = __builtin_amdgcn_mfma_f32_16x16x32_bf16(w1l[mt][0], bh0, a, 0, 0, 0);
        a = __builtin_amdgcn_mfma_f32_16x16x32_bf16(w1l[mt][1], bh1, a, 0, 0, 0);
        a = __builtin_amdgcn_mfma_f32_16x16x32_bf16(w1h[mt][0], bl0, a, 0, 0, 0);
        a = __builtin_amdgcn_mfma_f32_16x16x32_bf16(w1h[mt][1], bl1, a, 0, 0, 0);
        const float h0 = fmaxf(a[0], 0.f), h1 = fmaxf(a[1], 0.f);
        const float h2 = fmaxf(a[2], 0.f), h3 = fmaxf(a[3], 0.f);
        // MLP2 partials: this lane's m-slice (m = 16mt+4q+rr) for all 4 c
        const f32x4 w0 = *(const f32x4*)&W2[0 * HH + 16 * mt + 4 * q];
        const f32x4 w1 = *(const f32x4*)&W2[1 * HH + 16 * mt + 4 * q];
        const f32x4 w2 = *(const f32x4*)&W2[2 * HH + 16 * mt + 4 * q];
        const f32x4 w3 = *(const f32x4*)&W2[3 * HH + 16 * mt + 4 * q];
        p0 += h0 * w0[0] + h1 * w0[1] + h2 * w0[2] + h3 * w0[3];
        p1 += h0 * w1[0] + h1 * w1[1] + h2 * w1[2] + h3 * w1[3];
        p2 += h0 * w2[0] + h1 * w2[1] + h2 * w2[2] + h3 * w2[3];
        p3 += h0 * w3[0] + h1 * w3[1] + h2 * w3[2] + h3 * w3[3];
    }
    // reduce the m-slices across the 4 q-lanes (li, li+16, li+32, li+48)
    p0 += __shfl_xor(p0, 16); p0 += __shfl_xor(p0, 32);
    p1 += __shfl_xor(p1, 16); p1 += __shfl_xor(p1, 32);
    p2 += __shfl_xor(p2, 16); p2 += __shfl_xor(p2, 32);
    p3 += __shfl_xor(p3, 16); p3 += __shfl_xor(p3, 32);
    const float pv = (q == 0) ? p0 : (q == 1) ? p1 : (q == 2) ? p2 : p3;
    out[(size_t)(T0 + 16 * W + li) * 4 + q] = pv + b2[q];
}

extern "C" void kernel_launch(void* const* d_in, const int* in_sizes, int n_in,
                              void* d_out, int out_size, void* d_ws, size_t ws_size,
                              hipStream_t stream) {
    const float* emb  = (const float*)d_in[0];
    const float* W_ih = (const float*)d_in[1];
    const float* W_hh = (const float*)d_in[2];
    const float* b_ih = (const float*)d_in[3];
    const float* b_hh = (const float*)d_in[4];
    const float* W1   = (const float*)d_in[5];
    const float* b1   = (const float*)d_in[6];
    const float* W2   = (const float*)d_in[7];
    const float* b2   = (const float*)d_in[8];
    const int*   dn   = (const int*)d_in[9];

    int4v* wfrag = (int4v*)d_ws;     // 88 frags x 64 lanes x 16B = 90 KB
    float* o = (float*)d_out;

    prep_kernel<<<88, 64, 0, stream>>>(W_ih, W_hh, W1, wfrag);
    gru_kernel<<<NT / TPB, 256, 0, stream>>>(emb, wfrag, b_ih, b_hh,
                                             b1, W2, b2, dn, o);
}